// Round 6
// baseline (273.374 us; speedup 1.0000x reference)
//
#include <hip/hip_runtime.h>

typedef short bf16x8 __attribute__((ext_vector_type(8)));
typedef float f32x4 __attribute__((ext_vector_type(4)));
typedef unsigned short u16;

__device__ __forceinline__ u16 f2bf(float f) {
    unsigned u = __builtin_bit_cast(unsigned, f);
    return (u16)((u + 0x7fffu + ((u >> 16) & 1u)) >> 16);   // RNE
}

// ---------------- kernel 1 (fused prep): ------------------------------------
// blocks [0,1024):      xpad[b][r][d] bf16 (r<4096 zeros, 4096+t = x[b,t,:])
// blocks [1024,1064):   ApT/AmT[k][o][d] = (Mp +/- Mm)[k][d][o]
// blocks [1064,1192):   zero d_out (2 MiB); block 1064 also zeros the counter
__global__ void k_prep(const float* __restrict__ x, u16* __restrict__ xpad,
                       const float* __restrict__ Mp, const float* __restrict__ Mm,
                       float* __restrict__ ApT, float* __restrict__ AmT,
                       float* __restrict__ out, int* __restrict__ counter) {
    __shared__ float tp[64 * 65], tm[64 * 65];
    if (blockIdx.x < 1024) {
        int gid = blockIdx.x * 256 + threadIdx.x;
        int b   = gid >> 17;
        int rem = gid & 131071;
        int r   = rem >> 4;
        int c4  = rem & 15;
        u16 o0 = 0, o1 = 0, o2 = 0, o3 = 0;
        if (r >= 4096) {
            const f32x4 v = *(const f32x4*)(x + ((b << 12) + (r - 4096)) * 64 + c4 * 4);
            o0 = f2bf(v.x); o1 = f2bf(v.y); o2 = f2bf(v.z); o3 = f2bf(v.w);
        }
        u16* p = xpad + ((b << 13) + r) * 64 + c4 * 4;
        p[0] = o0; p[1] = o1; p[2] = o2; p[3] = o3;
    } else if (blockIdx.x < 1064) {
        const int k = blockIdx.x - 1024, tid = threadIdx.x;
        for (int f = tid; f < 4096; f += 256) {          // f = d*64 + o
            int d = f >> 6, o = f & 63;
            float p = Mp[k * 4096 + f], m = Mm[k * 4096 + f];
            tp[o * 65 + d] = p + m;
            tm[o * 65 + d] = p - m;
        }
        __syncthreads();
        for (int f = tid; f < 4096; f += 256) {          // f = o*64 + d
            int o = f >> 6, d = f & 63;
            ApT[k * 4096 + f] = tp[o * 65 + d];
            AmT[k * 4096 + f] = tm[o * 65 + d];
        }
    } else {
        const int bz = blockIdx.x - 1064;                // 128 blocks x 4096 floats
        if (bz == 0 && threadIdx.x == 0) *counter = 0;
        float* po = out + bz * 4096;
        #pragma unroll
        for (int i = 0; i < 4; ++i)
            *(f32x4*)(po + (threadIdx.x + i * 256) * 4) = (f32x4){0.f, 0.f, 0.f, 0.f};
    }
}

// ---------------- kernel 2: build Wtot[s][o][d] (bf16) -----------------------
// W[s][o][d] = sum_k phi[s,k]*(Mp + sgn(s)*Mm)[k,d,o]  (+ M[o,d,s] for s<3)
__global__ __launch_bounds__(256)
void k_build_w(const float* __restrict__ phi, const float* __restrict__ ApT,
               const float* __restrict__ AmT, const float* __restrict__ Mar,
               u16* __restrict__ wg) {
    const int sb = blockIdx.x;                 // 0..63  -> 64 s-values
    const int qb = blockIdx.y;                 // 0..15  -> 256 q = o*64+d
    const int s0 = sb * 64;
    const int q  = qb * 256 + threadIdx.x;
    const int o  = q >> 6, d = q & 63;

    float ap[40], am[40];
    #pragma unroll
    for (int k = 0; k < 40; ++k) { ap[k] = ApT[k * 4096 + q]; am[k] = AmT[k * 4096 + q]; }

    for (int j = 0; j < 64; j += 2) {
        const float* ph = phi + (s0 + j) * 40;           // wave-uniform -> s_load
        float a0 = 0.f, a1 = 0.f, b0 = 0.f, b1 = 0.f;
        #pragma unroll
        for (int k = 0; k < 40; k += 2) { a0 += ph[k] * ap[k]; a1 += ph[k + 1] * ap[k + 1]; }
        #pragma unroll
        for (int k = 0; k < 40; k += 2) { b0 += ph[40 + k] * am[k]; b1 += ph[41 + k] * am[k + 1]; }
        float ev = a0 + a1, ov = b0 + b1;
        int s = s0 + j;
        if (s < 3)     ev += Mar[o * 192 + d * 3 + s];
        if (s + 1 < 3) ov += Mar[o * 192 + d * 3 + s + 1];
        wg[(size_t)s * 4096 + q]       = f2bf(ev);
        wg[(size_t)(s + 1) * 4096 + q] = f2bf(ov);
    }
}

// ---------------- kernel 3: triangular conv-GEMM, s-parity waves -------------
// R5 inner geometry (proven 0-conflict): wave=(s-parity,batch), mt=8 x nt=4.
// R6: J-major dynamic task order (W L2-locality) + finer 32-s tasks (T=2112,
// tail idle 31% -> ~17%). Tile: 128 t x 2 batches x 32 s; x window 159 rows.
__global__ __launch_bounds__(256, 2)
void k_spectral(const u16* __restrict__ xpad, const u16* __restrict__ wg,
                float* __restrict__ out, int* __restrict__ counter) {
    __shared__ __align__(16) u16 xs[2 * 159 * 64];       // 39.75 KB x window
    __shared__ __align__(16) u16 wsm[2 * 64 * 64];       // 16 KB: [parity][o][chunk]
    __shared__ int sh;

    const int tid  = threadIdx.x;
    const int lane = tid & 63, w = tid >> 6;
    const int m15  = lane & 15, q4 = lane >> 4;
    const int par  = w >> 1, batch = w & 1;              // wave = (parity, batch)
    const int f0 = tid * 2, f1 = tid * 2 + 1;            // W staging granules
    const int l0 = (((f0 >> 3) * 8) + ((f0 & 7) ^ ((f0 >> 3) & 7))) * 8;
    const int l1 = (((f1 >> 3) * 8) + ((f1 & 7) ^ ((f1 >> 3) & 7))) * 8;

    for (;;) {
        __syncthreads();                                 // xs/wsm/sh reuse guard
        if (tid == 0) sh = atomicAdd(counter, 1);
        __syncthreads();
        const int U = sh;
        if (U >= 2112) break;

        // J-major order. Groups a=0..31: J in {4a..4a+3}, I in [a,32), each
        // J-column has cnt=32-a tasks. G(a) = 130a - 2a^2 cumulative.
        int a = 0;
        #pragma unroll 1
        while (a < 31 && (130 * (a + 1) - 2 * (a + 1) * (a + 1)) <= U) ++a;
        const int rem = U - (130 * a - 2 * a * a);
        const int cnt = 32 - a;
        const int J = 4 * a + rem / cnt;                 // s-block (32 wide)
        const int I = a + rem % cnt;                     // t-block (128 wide)
        const int t0 = I << 7, s0 = J << 5;
        const int base = 4096 + t0 - s0 - 31;            // in [3969, 8033]

        // prefetch W pair (s0, s0+1)
        const u16* wbase = wg + (size_t)s0 * 4096;
        bf16x8 pre[4];
        pre[0] = *(const bf16x8*)(wbase + f0 * 8);
        pre[1] = *(const bf16x8*)(wbase + f1 * 8);
        pre[2] = *(const bf16x8*)(wbase + 4096 + f0 * 8);
        pre[3] = *(const bf16x8*)(wbase + 4096 + f1 * 8);

        // ---- stage x window: 159 rows/batch (base+158 <= 8191 always) ----
        #pragma unroll
        for (int b = 0; b < 2; ++b) {
            for (int f = tid; f < 1272; f += 256) {      // 159 rows x 8 chunks
                int r = f >> 3, c = f & 7;
                bf16x8 v = *(const bf16x8*)(xpad + (size_t)((b << 13) + base + r) * 64 + c * 8);
                *(bf16x8*)(xs + ((b * 159 + r) * 8 + (c ^ (r & 7))) * 8) = v;
            }
        }

        f32x4 acc[8][4];
        #pragma unroll
        for (int mt = 0; mt < 8; ++mt)
            #pragma unroll
            for (int nt = 0; nt < 4; ++nt)
                acc[mt][nt] = (f32x4){0.f, 0.f, 0.f, 0.f};

        const u16* xb = xs + batch * (159 * 64);
        const u16* wpar = wsm + par * 4096;

        for (int j = 0; j < 16; ++j) {
            __syncthreads();                             // prev W reads complete
            *(bf16x8*)(wsm + l0)        = pre[0];
            *(bf16x8*)(wsm + l1)        = pre[1];
            *(bf16x8*)(wsm + 4096 + l0) = pre[2];
            *(bf16x8*)(wsm + 4096 + l1) = pre[3];
            __syncthreads();                             // W pair visible
            if (j < 15) {                                // prefetch next pair
                const u16* wp = wbase + (size_t)(2 * j + 2) * 4096;
                pre[0] = *(const bf16x8*)(wp + f0 * 8);
                pre[1] = *(const bf16x8*)(wp + f1 * 8);
                pre[2] = *(const bf16x8*)(wp + 4096 + f0 * 8);
                pre[3] = *(const bf16x8*)(wp + 4096 + f1 * 8);
            }
            const int ds = 2 * j + par;                  // this wave's s offset
            #pragma unroll
            for (int ks = 0; ks < 2; ++ks) {
                const int kq = ks * 4 + q4;
                bf16x8 bf[4];
                #pragma unroll
                for (int nt = 0; nt < 4; ++nt) {
                    int o = nt * 16 + m15;
                    bf[nt] = *(const bf16x8*)(wpar + (o * 8 + (kq ^ (o & 7))) * 8);
                }
                #pragma unroll
                for (int mt = 0; mt < 8; ++mt) {
                    int r = mt * 16 + m15 + 31 - ds;     // in [0, 158]
                    bf16x8 av = *(const bf16x8*)(xb + (r * 8 + (kq ^ (r & 7))) * 8);
                    #pragma unroll
                    for (int nt = 0; nt < 4; ++nt)
                        acc[mt][nt] = __builtin_amdgcn_mfma_f32_16x16x32_bf16(
                            av, bf[nt], acc[mt][nt], 0, 0, 0);
                }
            }
        }

        // ---- merge parity-1 partials into parity-0 accs via LDS (wsm dead) ----
        float* fs = (float*)wsm;                         // 4096 floats
        #pragma unroll
        for (int rd = 0; rd < 4; ++rd) {
            __syncthreads();
            if (par == 1) {
                #pragma unroll
                for (int i = 0; i < 8; ++i) {
                    int ti = rd * 8 + i;
                    *(f32x4*)(fs + (batch * 8 + i) * 256 + lane * 4) = acc[ti >> 2][ti & 3];
                }
            }
            __syncthreads();
            if (par == 0) {
                #pragma unroll
                for (int i = 0; i < 8; ++i) {
                    int ti = rd * 8 + i;
                    f32x4 v = *(const f32x4*)(fs + (batch * 8 + i) * 256 + lane * 4);
                    acc[ti >> 2][ti & 3] += v;
                }
            }
        }

        // ---- epilogue (parity-0 waves only): coalesced fp32 atomics ----
        if (par == 0) {
            #pragma unroll
            for (int mt = 0; mt < 8; ++mt) {
                int t = t0 + mt * 16 + q4 * 4;
                #pragma unroll
                for (int nt = 0; nt < 4; ++nt) {
                    int o = nt * 16 + m15;
                    float* op = out + (size_t)((batch << 12) + t) * 64 + o;
                    #pragma unroll
                    for (int r = 0; r < 4; ++r)
                        atomicAdd(op + r * 64, acc[mt][nt][r]);
                }
            }
        }
    }
}

// ---------------------------------------------------------------------------
extern "C" void kernel_launch(void* const* d_in, const int* in_sizes, int n_in,
                              void* d_out, int out_size, void* d_ws, size_t ws_size,
                              hipStream_t stream) {
    const float* x   = (const float*)d_in[0];   // (2, 4096, 64)
    const float* phi = (const float*)d_in[1];   // (4096, 40)
    const float* M   = (const float*)d_in[2];   // (64, 64, 3)
    const float* Mp  = (const float*)d_in[3];   // (40, 64, 64)
    const float* Mm  = (const float*)d_in[4];   // (40, 64, 64)
    float* out = (float*)d_out;                 // (2, 4096, 64)

    // ws: [0,4) counter | 4096: xpad 2 MiB | wg 32 MiB | ApT/AmT 2x640 KiB
    int* counter = (int*)d_ws;
    u16* xpad = (u16*)((char*)d_ws + 4096);
    u16* wg   = (u16*)((char*)d_ws + 4096 + 2097152);
    float* ApT = (float*)((char*)d_ws + 4096 + 2097152 + 33554432);
    float* AmT = ApT + 40 * 4096;

    k_prep<<<1192, 256, 0, stream>>>(x, xpad, Mp, Mm, ApT, AmT, out, counter);
    k_build_w<<<dim3(64, 16), 256, 0, stream>>>(phi, ApT, AmT, M, wg);
    k_spectral<<<512, 256, 0, stream>>>(xpad, wg, out, counter);
}

// Round 7
// 236.770 us; speedup vs baseline: 1.1546x; 1.1546x over previous
//
#include <hip/hip_runtime.h>

typedef short bf16x8 __attribute__((ext_vector_type(8)));
typedef float f32x4 __attribute__((ext_vector_type(4)));
typedef unsigned short u16;

__device__ __forceinline__ u16 f2bf(float f) {
    unsigned u = __builtin_bit_cast(unsigned, f);
    return (u16)((u + 0x7fffu + ((u >> 16) & 1u)) >> 16);   // RNE
}

// ---------------- kernel 1 (fused prep): ------------------------------------
// blocks [0,1024):      xpad[b][r][d] bf16 (r<4096 zeros, 4096+t = x[b,t,:])
// blocks [1024,1064):   ApT/AmT[k][o][d] = (Mp +/- Mm)[k][d][o]
// blocks [1064,1192):   zero d_out (2 MiB); block 1064 also zeros the counter
__global__ void k_prep(const float* __restrict__ x, u16* __restrict__ xpad,
                       const float* __restrict__ Mp, const float* __restrict__ Mm,
                       float* __restrict__ ApT, float* __restrict__ AmT,
                       float* __restrict__ out, int* __restrict__ counter) {
    __shared__ float tp[64 * 65], tm[64 * 65];
    if (blockIdx.x < 1024) {
        int gid = blockIdx.x * 256 + threadIdx.x;
        int b   = gid >> 17;
        int rem = gid & 131071;
        int r   = rem >> 4;
        int c4  = rem & 15;
        u16 o0 = 0, o1 = 0, o2 = 0, o3 = 0;
        if (r >= 4096) {
            const f32x4 v = *(const f32x4*)(x + ((b << 12) + (r - 4096)) * 64 + c4 * 4);
            o0 = f2bf(v.x); o1 = f2bf(v.y); o2 = f2bf(v.z); o3 = f2bf(v.w);
        }
        u16* p = xpad + ((b << 13) + r) * 64 + c4 * 4;
        p[0] = o0; p[1] = o1; p[2] = o2; p[3] = o3;
    } else if (blockIdx.x < 1064) {
        const int k = blockIdx.x - 1024, tid = threadIdx.x;
        for (int f = tid; f < 4096; f += 256) {          // f = d*64 + o
            int d = f >> 6, o = f & 63;
            float p = Mp[k * 4096 + f], m = Mm[k * 4096 + f];
            tp[o * 65 + d] = p + m;
            tm[o * 65 + d] = p - m;
        }
        __syncthreads();
        for (int f = tid; f < 4096; f += 256) {          // f = o*64 + d
            int o = f >> 6, d = f & 63;
            ApT[k * 4096 + f] = tp[o * 65 + d];
            AmT[k * 4096 + f] = tm[o * 65 + d];
        }
    } else {
        const int bz = blockIdx.x - 1064;                // 128 blocks x 4096 floats
        if (bz == 0 && threadIdx.x == 0) *counter = 0;
        float* po = out + bz * 4096;
        #pragma unroll
        for (int i = 0; i < 4; ++i)
            *(f32x4*)(po + (threadIdx.x + i * 256) * 4) = (f32x4){0.f, 0.f, 0.f, 0.f};
    }
}

// ---------------- kernel 2: build Wtot[s][o][d] (bf16) -----------------------
// W[s][o][d] = sum_k phi[s,k]*(Mp + sgn(s)*Mm)[k,d,o]  (+ M[o,d,s] for s<3)
__global__ __launch_bounds__(256)
void k_build_w(const float* __restrict__ phi, const float* __restrict__ ApT,
               const float* __restrict__ AmT, const float* __restrict__ Mar,
               u16* __restrict__ wg) {
    const int sb = blockIdx.x;                 // 0..63  -> 64 s-values
    const int qb = blockIdx.y;                 // 0..15  -> 256 q = o*64+d
    const int s0 = sb * 64;
    const int q  = qb * 256 + threadIdx.x;
    const int o  = q >> 6, d = q & 63;

    float ap[40], am[40];
    #pragma unroll
    for (int k = 0; k < 40; ++k) { ap[k] = ApT[k * 4096 + q]; am[k] = AmT[k * 4096 + q]; }

    for (int j = 0; j < 64; j += 2) {
        const float* ph = phi + (s0 + j) * 40;           // wave-uniform -> s_load
        float a0 = 0.f, a1 = 0.f, b0 = 0.f, b1 = 0.f;
        #pragma unroll
        for (int k = 0; k < 40; k += 2) { a0 += ph[k] * ap[k]; a1 += ph[k + 1] * ap[k + 1]; }
        #pragma unroll
        for (int k = 0; k < 40; k += 2) { b0 += ph[40 + k] * am[k]; b1 += ph[41 + k] * am[k + 1]; }
        float ev = a0 + a1, ov = b0 + b1;
        int s = s0 + j;
        if (s < 3)     ev += Mar[o * 192 + d * 3 + s];
        if (s + 1 < 3) ov += Mar[o * 192 + d * 3 + s + 1];
        wg[(size_t)s * 4096 + q]       = f2bf(ev);
        wg[(size_t)(s + 1) * 4096 + q] = f2bf(ov);
    }
}

// ---------------- kernel 3: triangular conv-GEMM, s-parity waves -------------
// R5 inner geometry (proven 0-conflict): wave=(s-parity,batch), mt=8 x nt=4,
// 64-s tiles, 17.3M coalesced atomics.
// R7 schedule: J-major unit order (W L2-resident, proven by R6's FETCH drop)
// + tail taper: units [0,992) as full 64-s tasks, units [992,1056) split into
// 128 half (32-s) tasks consumed last -> schedule util 69% -> ~83%.
__global__ __launch_bounds__(256, 2)
void k_spectral(const u16* __restrict__ xpad, const u16* __restrict__ wg,
                float* __restrict__ out, int* __restrict__ counter) {
    __shared__ __align__(16) u16 xs[2 * 191 * 64];       // 47.75 KB x window
    __shared__ __align__(16) u16 wsm[2 * 64 * 64];       // 16 KB: [parity][o][chunk]
    __shared__ int sh;

    const int tid  = threadIdx.x;
    const int lane = tid & 63, w = tid >> 6;
    const int m15  = lane & 15, q4 = lane >> 4;
    const int par  = w >> 1, batch = w & 1;              // wave = (parity, batch)
    const int f0 = tid * 2, f1 = tid * 2 + 1;            // W staging granules
    const int l0 = (((f0 >> 3) * 8) + ((f0 & 7) ^ ((f0 >> 3) & 7))) * 8;
    const int l1 = (((f1 >> 3) * 8) + ((f1 & 7) ^ ((f1 >> 3) & 7))) * 8;

    for (;;) {
        __syncthreads();                                 // xs/wsm/sh reuse guard
        if (tid == 0) sh = atomicAdd(counter, 1);
        __syncthreads();
        const int U = sh;
        if (U >= 1120) break;

        // taper: U<992 -> full unit; else half task (32-s) of unit 992+(U-992)/2
        int mu = U, shalf = 0, slen = 64;
        if (U >= 992) { mu = 992 + ((U - 992) >> 1); shalf = (U - 992) & 1; slen = 32; }
        // J-major unit decode: group g=J>>1, G(g)=g(65-g), column cnt=32-g
        int g = 0;
        #pragma unroll 1
        while (g < 31 && (g + 1) * (64 - g) <= mu) ++g;
        const int rem = mu - g * (65 - g);
        const int cnt = 32 - g;
        const int col = (rem >= cnt) ? 1 : 0;
        const int J = 2 * g + col;
        const int I = g + (col ? rem - cnt : rem);
        const int t0 = I << 7, s0 = (J << 6) + (shalf << 5);
        const int nrows = 127 + slen;
        const int jmax = slen >> 1;
        const int base = 4096 + t0 - s0 - (slen - 1);    // >= 3969; base+nrows-1 <= 8191

        // prefetch W pair (s0, s0+1)
        const u16* wbase = wg + (size_t)s0 * 4096;
        bf16x8 pre[4];
        pre[0] = *(const bf16x8*)(wbase + f0 * 8);
        pre[1] = *(const bf16x8*)(wbase + f1 * 8);
        pre[2] = *(const bf16x8*)(wbase + 4096 + f0 * 8);
        pre[3] = *(const bf16x8*)(wbase + 4096 + f1 * 8);

        // ---- stage x window: nrows rows/batch ----
        #pragma unroll
        for (int b = 0; b < 2; ++b) {
            #pragma unroll 1
            for (int f = tid; f < nrows * 8; f += 256) {
                int r = f >> 3, c = f & 7;
                bf16x8 v = *(const bf16x8*)(xpad + (size_t)((b << 13) + base + r) * 64 + c * 8);
                *(bf16x8*)(xs + ((b * 191 + r) * 8 + (c ^ (r & 7))) * 8) = v;
            }
        }

        f32x4 acc[8][4];
        #pragma unroll
        for (int mt = 0; mt < 8; ++mt)
            #pragma unroll
            for (int nt = 0; nt < 4; ++nt)
                acc[mt][nt] = (f32x4){0.f, 0.f, 0.f, 0.f};

        const u16* xb = xs + batch * (191 * 64);
        const u16* wpar = wsm + par * 4096;

        #pragma unroll 1
        for (int j = 0; j < jmax; ++j) {
            __syncthreads();                             // prev W reads complete
            *(bf16x8*)(wsm + l0)        = pre[0];
            *(bf16x8*)(wsm + l1)        = pre[1];
            *(bf16x8*)(wsm + 4096 + l0) = pre[2];
            *(bf16x8*)(wsm + 4096 + l1) = pre[3];
            __syncthreads();                             // W pair visible
            if (j < jmax - 1) {                          // prefetch next pair
                const u16* wp = wbase + (size_t)(2 * j + 2) * 4096;
                pre[0] = *(const bf16x8*)(wp + f0 * 8);
                pre[1] = *(const bf16x8*)(wp + f1 * 8);
                pre[2] = *(const bf16x8*)(wp + 4096 + f0 * 8);
                pre[3] = *(const bf16x8*)(wp + 4096 + f1 * 8);
            }
            const int ds = 2 * j + par;                  // this wave's s offset
            #pragma unroll
            for (int ks = 0; ks < 2; ++ks) {
                const int kq = ks * 4 + q4;
                bf16x8 bf[4];
                #pragma unroll
                for (int nt = 0; nt < 4; ++nt) {
                    int o = nt * 16 + m15;
                    bf[nt] = *(const bf16x8*)(wpar + (o * 8 + (kq ^ (o & 7))) * 8);
                }
                #pragma unroll
                for (int mt = 0; mt < 8; ++mt) {
                    int r = mt * 16 + m15 + (slen - 1) - ds;   // in [0, nrows-1]
                    bf16x8 av = *(const bf16x8*)(xb + (r * 8 + (kq ^ (r & 7))) * 8);
                    #pragma unroll
                    for (int nt = 0; nt < 4; ++nt)
                        acc[mt][nt] = __builtin_amdgcn_mfma_f32_16x16x32_bf16(
                            av, bf[nt], acc[mt][nt], 0, 0, 0);
                }
            }
        }

        // ---- merge parity-1 partials into parity-0 accs via LDS (wsm dead) ----
        float* fs = (float*)wsm;                         // 4096 floats
        #pragma unroll
        for (int rd = 0; rd < 4; ++rd) {
            __syncthreads();
            if (par == 1) {
                #pragma unroll
                for (int i = 0; i < 8; ++i) {
                    int ti = rd * 8 + i;
                    *(f32x4*)(fs + (batch * 8 + i) * 256 + lane * 4) = acc[ti >> 2][ti & 3];
                }
            }
            __syncthreads();
            if (par == 0) {
                #pragma unroll
                for (int i = 0; i < 8; ++i) {
                    int ti = rd * 8 + i;
                    f32x4 v = *(const f32x4*)(fs + (batch * 8 + i) * 256 + lane * 4);
                    acc[ti >> 2][ti & 3] += v;
                }
            }
        }

        // ---- epilogue (parity-0 waves only): coalesced fp32 atomics ----
        if (par == 0) {
            #pragma unroll
            for (int mt = 0; mt < 8; ++mt) {
                int t = t0 + mt * 16 + q4 * 4;
                #pragma unroll
                for (int nt = 0; nt < 4; ++nt) {
                    int o = nt * 16 + m15;
                    float* op = out + (size_t)((batch << 12) + t) * 64 + o;
                    #pragma unroll
                    for (int r = 0; r < 4; ++r)
                        atomicAdd(op + r * 64, acc[mt][nt][r]);
                }
            }
        }
    }
}

// ---------------------------------------------------------------------------
extern "C" void kernel_launch(void* const* d_in, const int* in_sizes, int n_in,
                              void* d_out, int out_size, void* d_ws, size_t ws_size,
                              hipStream_t stream) {
    const float* x   = (const float*)d_in[0];   // (2, 4096, 64)
    const float* phi = (const float*)d_in[1];   // (4096, 40)
    const float* M   = (const float*)d_in[2];   // (64, 64, 3)
    const float* Mp  = (const float*)d_in[3];   // (40, 64, 64)
    const float* Mm  = (const float*)d_in[4];   // (40, 64, 64)
    float* out = (float*)d_out;                 // (2, 4096, 64)

    // ws: [0,4) counter | 4096: xpad 2 MiB | wg 32 MiB | ApT/AmT 2x640 KiB
    int* counter = (int*)d_ws;
    u16* xpad = (u16*)((char*)d_ws + 4096);
    u16* wg   = (u16*)((char*)d_ws + 4096 + 2097152);
    float* ApT = (float*)((char*)d_ws + 4096 + 2097152 + 33554432);
    float* AmT = ApT + 40 * 4096;

    k_prep<<<1192, 256, 0, stream>>>(x, xpad, Mp, Mm, ApT, AmT, out, counter);
    k_build_w<<<dim3(64, 16), 256, 0, stream>>>(phi, ApT, AmT, M, wg);
    k_spectral<<<512, 256, 0, stream>>>(xpad, wg, out, counter);
}